// Round 2
// baseline (180.849 us; speedup 1.0000x reference)
//
#include <hip/hip_runtime.h>
#include <hip/hip_bf16.h>

// Word embedding gather: out[token, :] = weight[ids[token], :]
// ids: (8192,) int32 ; weight: (32000, 1024) fp32 ; out: (8192, 1024) fp32
//
// R2: batch 4 tokens per block to get ILP on the row loads. Each block
// (256 threads) loads 4 ids up front (scalar, independent), then each lane
// issues 4 independent float4 loads (64 B/lane in flight) and 4 stores.
// This breaks the R1 structure's 1-outstanding-load-per-lane dependent
// chain (id -> row -> store) that left waves latency-stalled.

#define DIM4 256  // 1024 floats / 4 per float4
#define TPB  4    // tokens per block

__global__ __launch_bounds__(256) void embed_gather_kernel(
    const int* __restrict__ ids,
    const float4* __restrict__ weight,
    float4* __restrict__ out,
    int n_tokens)
{
    const int tid  = threadIdx.x;
    const int base = blockIdx.x * TPB;

    // All 4 id loads are independent scalar loads (uniform addresses).
    int id[TPB];
#pragma unroll
    for (int k = 0; k < TPB; ++k) {
        int t = base + k;
        id[k] = (t < n_tokens) ? ids[t] : 0;
    }

    // 4 independent 16B loads per lane -> 64 B/lane in flight.
    float4 r[TPB];
#pragma unroll
    for (int k = 0; k < TPB; ++k)
        r[k] = weight[(size_t)id[k] * DIM4 + tid];

#pragma unroll
    for (int k = 0; k < TPB; ++k) {
        int t = base + k;
        if (t < n_tokens)
            out[(size_t)t * DIM4 + tid] = r[k];
    }
}

extern "C" void kernel_launch(void* const* d_in, const int* in_sizes, int n_in,
                              void* d_out, int out_size, void* d_ws, size_t ws_size,
                              hipStream_t stream) {
    const int*    ids    = (const int*)d_in[0];      // input_ids, 8192 int32
    const float4* weight = (const float4*)d_in[1];   // (32000, 1024) fp32
    float4*       out    = (float4*)d_out;           // (8192, 1024) fp32

    const int n_tokens = in_sizes[0];                // 8192
    const int grid     = (n_tokens + TPB - 1) / TPB; // 2048 blocks

    embed_gather_kernel<<<grid, DIM4, 0, stream>>>(ids, weight, out, n_tokens);
}

// Round 4
// 180.413 us; speedup vs baseline: 1.0024x; 1.0024x over previous
//
#include <hip/hip_runtime.h>
#include <hip/hip_bf16.h>

// Word embedding gather: out[token, :] = weight[ids[token], :]
// ids: (8192,) int32 ; weight: (32000, 1024) fp32 ; out: (8192, 1024) fp32
//
// R4 = R3 with the nontemporal-store compile error fixed: the builtin needs
// a native clang vector type, not HIP_vector_type. 8 tokens/block (8
// independent 1 KB row loads in flight per wave), 1024 blocks, nontemporal
// stores for `out` (streaming, never re-read -> keep the 131 MB weight
// working set unpolluted in L2/L3).

typedef float floatx4 __attribute__((ext_vector_type(4)));

#define DIM4 256  // 1024 floats / 4 per float4
#define TPB  8    // tokens per block

__global__ __launch_bounds__(256) void embed_gather_kernel(
    const int* __restrict__ ids,
    const floatx4* __restrict__ weight,
    floatx4* __restrict__ out,
    int n_tokens)
{
    const int tid  = threadIdx.x;
    const int base = blockIdx.x * TPB;

    // Wave-uniform id loads (compiler emits scalar loads), all independent.
    int id[TPB];
#pragma unroll
    for (int k = 0; k < TPB; ++k) {
        int t = base + k;
        id[k] = (t < n_tokens) ? ids[t] : 0;
    }

    // 8 independent 16B loads per lane -> 128 B/lane in flight.
    floatx4 r[TPB];
#pragma unroll
    for (int k = 0; k < TPB; ++k)
        r[k] = weight[(size_t)id[k] * DIM4 + tid];

#pragma unroll
    for (int k = 0; k < TPB; ++k) {
        int t = base + k;
        if (t < n_tokens)
            __builtin_nontemporal_store(r[k], &out[(size_t)t * DIM4 + tid]);
    }
}

extern "C" void kernel_launch(void* const* d_in, const int* in_sizes, int n_in,
                              void* d_out, int out_size, void* d_ws, size_t ws_size,
                              hipStream_t stream) {
    const int*     ids    = (const int*)d_in[0];      // input_ids, 8192 int32
    const floatx4* weight = (const floatx4*)d_in[1];  // (32000, 1024) fp32
    floatx4*       out    = (floatx4*)d_out;          // (8192, 1024) fp32

    const int n_tokens = in_sizes[0];                 // 8192
    const int grid     = (n_tokens + TPB - 1) / TPB;  // 1024 blocks

    embed_gather_kernel<<<grid, DIM4, 0, stream>>>(ids, weight, out, n_tokens);
}